// Round 7
// baseline (386.908 us; speedup 1.0000x reference)
//
#include <hip/hip_runtime.h>

// FoutLayer: out = x@wc + bias + mean_{j<32} (x@wn)[dst[n*32+j]]
// N=50000, C=512, DEG=32. src = repeat(arange(N),32) -> node n's edges are
// dst[32n..32n+31], counts == 32 (contiguous-segment mean, no atomics).
//
// R8 (this round): gather = persistent blocks + 8-deep load batches.
//  - R7 post-mortem: busy/occ fell 0.81->0.53 at constant 112 us -> gather is
//    stalled on beta-load latency, not issue. Two candidate limiters left:
//    MLP (VGPR=32 caps in-flight loads ~4) and block churn (50000 tiny
//    blocks -> occupancy 66% with zero resource pressure).
//  - fix both: grid = 2048 persistent blocks (8/CU, all resident; phase =
//    b&7 keeps XCD pinning), grid-stride over 6250 octets/phase; inner loop
//    as 2 explicit batches of 8 independent loads (8 in flight/wave).
//  - pre-committed read: dur 85-95 us => latency/churn was it; dur ~105-110
//    at occ>=85 => L2 random-request floor, gather done, attack GEMM next.
// R7: half-node groups, bpermute broadcast, 32-bit voffset vs uniform base.
// R5: dst u16; packed epilogues; phase-sliced fp8 beta, XCD-pinned.

#define M_ROWS 50000
#define DEG 32
#define NE (M_ROWS * DEG)
#define SLICE_DW 800000   // 50000 nodes * 16 dwords (64 B) per phase

typedef short s16x8 __attribute__((ext_vector_type(8)));
typedef float f32x4 __attribute__((ext_vector_type(4)));
typedef float f32x2 __attribute__((ext_vector_type(2)));
typedef unsigned int u32x2 __attribute__((ext_vector_type(2)));

__device__ __forceinline__ unsigned short f2bf(float f) {
  union { float f; unsigned int u; } c; c.f = f;
  unsigned int u = c.u;
  u += 0x7fffu + ((u >> 16) & 1u);   // round-to-nearest-even
  return (unsigned short)(u >> 16);
}

__device__ __forceinline__ float bfhi(unsigned int u) {
  return __uint_as_float(u & 0xffff0000u);
}
__device__ __forceinline__ float bflo(unsigned int u) {
  return __uint_as_float(u << 16);
}

__device__ __forceinline__ void gl_lds16(const void* g, void* l) {
  __builtin_amdgcn_global_load_lds(
      (const __attribute__((address_space(1))) unsigned int*)g,
      (__attribute__((address_space(3))) unsigned int*)l, 16, 0, 0);
}

// ---- K0a: x f32 -> bf16 (each thread: 8 elems) --------------------------
__global__ __launch_bounds__(256) void k_convert_x(
    const float* __restrict__ x, unsigned short* __restrict__ xb) {
  const size_t base = ((size_t)blockIdx.x * 256 + threadIdx.x) * 8;
  const float4 a = *(const float4*)(x + base);
  const float4 b = *(const float4*)(x + base + 4);
  union { unsigned short u[8]; uint4 v; } p;
  p.u[0] = f2bf(a.x); p.u[1] = f2bf(a.y); p.u[2] = f2bf(a.z); p.u[3] = f2bf(a.w);
  p.u[4] = f2bf(b.x); p.u[5] = f2bf(b.y); p.u[6] = f2bf(b.z); p.u[7] = f2bf(b.w);
  *(uint4*)(xb + base) = p.v;
}

// ---- K0b: W = [wc|wn] -> Wt[n][k] bf16 (transposed, k-contiguous) -------
__global__ __launch_bounds__(256) void k_convert_w(
    const float* __restrict__ wc, const float* __restrict__ wn,
    unsigned short* __restrict__ wt) {
  const int k = blockIdx.x;            // 0..511
  const int n4 = threadIdx.x * 4;      // 0..1020
  const float* src = (n4 < 512) ? (wc + (size_t)k * 512 + n4)
                                : (wn + (size_t)k * 512 + (n4 - 512));
  const float4 v = *(const float4*)src;
  wt[(size_t)(n4 + 0) * 512 + k] = f2bf(v.x);
  wt[(size_t)(n4 + 1) * 512 + k] = f2bf(v.y);
  wt[(size_t)(n4 + 2) * 512 + k] = f2bf(v.z);
  wt[(size_t)(n4 + 3) * 512 + k] = f2bf(v.w);
}

// ---- K0c: dst int32 -> u16 (N=50000 < 65536) ----------------------------
__global__ __launch_bounds__(256) void k_convert_dst(
    const int* __restrict__ dst, unsigned short* __restrict__ d16) {
  const size_t base = ((size_t)blockIdx.x * 256 + threadIdx.x) * 8;
  if (base >= NE) return;
  const int4 a = *(const int4*)(dst + base);
  const int4 b = *(const int4*)(dst + base + 4);
  union { unsigned short u[8]; uint4 v; } p;
  p.u[0] = (unsigned short)a.x; p.u[1] = (unsigned short)a.y;
  p.u[2] = (unsigned short)a.z; p.u[3] = (unsigned short)a.w;
  p.u[4] = (unsigned short)b.x; p.u[5] = (unsigned short)b.y;
  p.u[6] = (unsigned short)b.z; p.u[7] = (unsigned short)b.w;
  *(uint4*)(d16 + base) = p.v;
}

// ---- K1: bf16 MFMA GEMM, 128x128 tile, BK=64, swizzled LDS --------------
// 1D grid 3128 blocks, XCD-affine (mt,nt) mapping: XCD c = g%8 owns m-tiles
// {c, c+8, ...}, each with its 8 n-tiles consecutive -> A-tile L2 reuse.
// LDS layout: slot (row, seg) holds global k-segment seg^(row&7) -> all
// ds_read_b128 land 2 lanes/bank (free).
__global__ __launch_bounds__(256) void k_gemm(
    const unsigned short* __restrict__ xb,   // [M][512] bf16
    const unsigned short* __restrict__ wt,   // [1024][512] bf16
    const float* __restrict__ bias,          // [512]
    unsigned short* __restrict__ alphab,     // [M][8][32] u32 packed bf16
    unsigned char* __restrict__ betaf8) {    // [8][M][16] u32 packed fp8
  __shared__ __attribute__((aligned(16))) unsigned short As[128 * 64];
  __shared__ __attribute__((aligned(16))) unsigned short Bs[128 * 64];

  const int tid = threadIdx.x;
  const int g = blockIdx.x;
  int mt, nt;
  if (g < 3072) {
    const int c = g & 7, j = g >> 3;
    nt = j & 7; mt = (j >> 3) * 8 + c;
  } else {
    const int r = g - 3072;
    mt = 384 + (r >> 3); nt = r & 7;
  }
  const int n0 = nt * 128;
  const int m0 = mt * 128;

  const int wv = tid >> 6;
  const int l = tid & 63;
  const int lm = l & 15;
  const int quad = l >> 4;
  const int mb = (wv >> 1) * 64;
  const int nb = (wv & 1) * 64;

  // staging addresses (hoisted): 4 chunks each of A and B per thread
  size_t aofs[4], bofs[4];
  int ldst[4];
#pragma unroll
  for (int s = 0; s < 4; ++s) {
    const int c = s * 256 + tid;
    const int row = c >> 3;              // 0..127
    const int seg = c & 7;               // LDS slot segment
    const int sg = seg ^ (row & 7);      // global segment fetched into it
    int am = m0 + row; if (am >= M_ROWS) am = M_ROWS - 1;
    aofs[s] = (size_t)am * 512 + sg * 8;
    bofs[s] = (size_t)(n0 + row) * 512 + sg * 8;
    ldst[s] = (s * 256 + (tid & ~63)) * 16;
  }

  f32x4 acc[4][4];
#pragma unroll
  for (int i = 0; i < 4; ++i)
#pragma unroll
    for (int j = 0; j < 4; ++j) acc[i][j] = (f32x4)(0.0f);

  for (int kt = 0; kt < 8; ++kt) {
    const int k0 = kt * 64;
    __syncthreads();
#pragma unroll
    for (int s = 0; s < 4; ++s) {
      gl_lds16(xb + aofs[s] + k0, (char*)As + ldst[s]);
      gl_lds16(wt + bofs[s] + k0, (char*)Bs + ldst[s]);
    }
    __syncthreads();   // drains vmcnt for global_load_lds

#pragma unroll
    for (int h = 0; h < 2; ++h) {
      s16x8 af[4], bfr[4];
#pragma unroll
      for (int i = 0; i < 4; ++i) {
        const int R = mb + 16 * i + lm;
        af[i] = *(const s16x8*)&As[R * 64 + (((h * 4 + quad) ^ (R & 7)) << 3)];
      }
#pragma unroll
      for (int j = 0; j < 4; ++j) {
        const int R = nb + 16 * j + lm;
        bfr[j] = *(const s16x8*)&Bs[R * 64 + (((h * 4 + quad) ^ (R & 7)) << 3)];
      }
#pragma unroll
      for (int i = 0; i < 4; ++i)
#pragma unroll
        for (int j = 0; j < 4; ++j)
          acc[i][j] = __builtin_amdgcn_mfma_f32_16x16x32_bf16(
              af[i], bfr[j], acc[i][j], 0, 0, 0);
    }
  }

  // Packed epilogue. grp64 = global 64-channel group (0..15).
  // Within a group, dword d holds channels {d, 16+d, 32+d, 48+d} = lane
  // lm's j=0..3 accumulator columns -> no cross-lane traffic needed.
  const bool isAlpha = (n0 < 512);
  const int grp64 = (n0 + nb) >> 6;
  float b4[4];
#pragma unroll
  for (int j = 0; j < 4; ++j)
    b4[j] = isAlpha ? bias[n0 + nb + 16 * j + lm] : 0.0f;

  if (isAlpha) {
    unsigned int* ap = (unsigned int*)alphab;   // [M][8][32] dwords
#pragma unroll
    for (int i = 0; i < 4; ++i) {
#pragma unroll
      for (int r = 0; r < 4; ++r) {
        const int m = m0 + mb + 16 * i + quad * 4 + r;
        if (m < M_ROWS) {
          u32x2 v;
          v.x = (unsigned int)f2bf(acc[i][0][r] + b4[0]) |
                ((unsigned int)f2bf(acc[i][1][r] + b4[1]) << 16);
          v.y = (unsigned int)f2bf(acc[i][2][r] + b4[2]) |
                ((unsigned int)f2bf(acc[i][3][r] + b4[3]) << 16);
          *(u32x2*)(ap + (size_t)m * 256 + grp64 * 32 + 2 * lm) = v;
        }
      }
    }
  } else {
    unsigned int* bp = (unsigned int*)betaf8 + (size_t)(grp64 - 8) * SLICE_DW;
#pragma unroll
    for (int i = 0; i < 4; ++i) {
#pragma unroll
      for (int r = 0; r < 4; ++r) {
        const int m = m0 + mb + 16 * i + quad * 4 + r;
        if (m < M_ROWS) {
          int p = __builtin_amdgcn_cvt_pk_fp8_f32(acc[i][0][r], acc[i][1][r], 0, false);
          p = __builtin_amdgcn_cvt_pk_fp8_f32(acc[i][2][r], acc[i][3][r], p, true);
          bp[(size_t)m * 16 + lm] = (unsigned int)p;
        }
      }
    }
  }
}

// ---- K2: out = alpha + mean(beta_fp8 rows), persistent blocks -----------
// Grid = 2048 blocks (8/CU, all resident). Block b: phase = b&7 (== XCD id,
// pins the 3.2 MB slice), grid-stride q = (b>>3) + 256k over 6250 octets.
// Wave = 2 nodes; 16-lane group = half node (16 edges); shfl_xor(16) merge.
// Inner loop: 2 explicit batches of 8 independent loads (8 in flight).
template <typename IT>
__global__ __launch_bounds__(256, 8) void k_gather(
    const IT* __restrict__ dst, const unsigned int* __restrict__ beta32,
    const unsigned int* __restrict__ alpha32, float* __restrict__ out) {
  const int b = blockIdx.x;              // 0..2047
  const int phase = b & 7;               // == XCD id
  const int tid = threadIdx.x;
  const int w = tid >> 6;
  const int l = tid & 63;
  const int lm = l & 15;                 // dword (4 ch) in 64-B row
  const int abase = (l & 48) << 2;       // bpermute src lanes = (l&48)+e
  const unsigned lmoff = (unsigned)lm * 4u;
  const char* base = (const char*)(beta32 + (size_t)phase * SLICE_DW);
  const float s = 1.0f / 32.0f;
  const int nsub = w * 2 + ((l >> 5) & 1);   // node-in-octet/2 for writers

  for (int q = b >> 3; q < 6250; q += 256) {
    // lane stages one edge row-index (wave's 64 edges = its 2 nodes)
    const int vstage = (int)(unsigned)__builtin_nontemporal_load(
        dst + (size_t)q * 256 + tid);

    f32x2 s01 = (f32x2)(0.0f), s23 = (f32x2)(0.0f);
#pragma unroll
    for (int h = 0; h < 2; ++h) {
      unsigned int bb[8];
#pragma unroll
      for (int e = 0; e < 8; ++e) {
        const int row = __builtin_amdgcn_ds_bpermute(
            abase + ((h * 8 + e) << 2), vstage);
        bb[e] = *(const unsigned int*)(base + (((unsigned)row << 6) + lmoff));
      }
#pragma unroll
      for (int e = 0; e < 8; ++e) {
        s01 += __builtin_amdgcn_cvt_pk_f32_fp8(bb[e], false); // ch lm,16+lm
        s23 += __builtin_amdgcn_cvt_pk_f32_fp8(bb[e], true);  // ch 32+lm,48+lm
      }
    }

    // merge the two half-node groups (lanes l <-> l^16)
    s01.x += __shfl_xor(s01.x, 16, 64);
    s01.y += __shfl_xor(s01.y, 16, 64);
    s23.x += __shfl_xor(s23.x, 16, 64);
    s23.y += __shfl_xor(s23.y, 16, 64);

    if (!(l & 16)) {                     // lanes 0-15 (node A), 32-47 (node B)
      const int node = q * 8 + nsub;
      const u32x2 av = __builtin_nontemporal_load(
          (const u32x2*)(alpha32 + (size_t)node * 256 + phase * 32) + lm);
      float* ob = out + (size_t)node * 512 + phase * 64;
      __builtin_nontemporal_store(bflo(av.x) + s01.x * s, ob + lm);
      __builtin_nontemporal_store(bfhi(av.x) + s01.y * s, ob + 16 + lm);
      __builtin_nontemporal_store(bflo(av.y) + s23.x * s, ob + 32 + lm);
      __builtin_nontemporal_store(bfhi(av.y) + s23.y * s, ob + 48 + lm);
    }
  }
}

extern "C" void kernel_launch(void* const* d_in, const int* in_sizes, int n_in,
                              void* d_out, int out_size, void* d_ws, size_t ws_size,
                              hipStream_t stream) {
  const float* x    = (const float*)d_in[0];
  const float* wc   = (const float*)d_in[1];
  const float* wn   = (const float*)d_in[2];
  const float* bias = (const float*)d_in[3];
  const int*   ei   = (const int*)d_in[4];   // [2][E] int32; dst = ei + E
  float* out = (float*)d_out;

  char* ws = (char*)d_ws;
  unsigned short* xb     = (unsigned short*)ws;                  // 51,200,000 B
  unsigned short* wt     = (unsigned short*)(ws + 51200000);     //  1,048,576 B
  unsigned short* alphab = (unsigned short*)(ws + 52248576);     // 51,200,000 B
  unsigned char*  betaf8 = (unsigned char*)(ws + 103448576);     // 25,600,000 B
  unsigned short* d16    = (unsigned short*)(ws + 129048576);    //  3,200,000 B
  const bool u16ok = (ws_size >= (size_t)129048576 + 3200000);

  k_convert_x<<<12500, 256, 0, stream>>>(x, xb);
  k_convert_w<<<512, 256, 0, stream>>>(wc, wn, wt);
  if (u16ok) k_convert_dst<<<782, 256, 0, stream>>>(ei + NE, d16);
  k_gemm<<<3128, 256, 0, stream>>>(xb, wt, bias, alphab, betaf8);
  if (u16ok) {
    k_gather<unsigned short><<<2048, 256, 0, stream>>>(
        d16, (const unsigned int*)betaf8, (const unsigned int*)alphab, out);
  } else {
    k_gather<int><<<2048, 256, 0, stream>>>(
        ei + NE, (const unsigned int*)betaf8, (const unsigned int*)alphab, out);
  }
}

// Round 8
// 348.551 us; speedup vs baseline: 1.1100x; 1.1100x over previous
//
#include <hip/hip_runtime.h>

// FoutLayer: out = x@wc + bias + mean_{j<32} (x@wn)[dst[n*32+j]]
// N=50000, C=512, DEG=32. src = repeat(arange(N),32) -> node n's edges are
// dst[32n..32n+31], counts == 32 (contiguous-segment mean, no atomics).
//
// R9 (this round): beta re-sliced 8x64B -> 4 phase-pairs x 128B rows.
//  - R4-R8 post-mortem: four different gather structures all converge at
//    ~6 random 64-B L2 requests/cycle/XCD (issue<=48%, L1 0.2 txn/cy/CU,
//    HBM 15% -> none binding). That is a cache-line PROBE-rate floor.
//  - Fix: double the row to one full 128-B line -> probes halve (12.8M ->
//    6.4M). Each edge read = 32 lanes x 4B = one line-aligned probe.
//  - pair = b&3 pins each 6.4 MB pair-slice to XCDs {p, p+4}; ~38% of reads
//    spill from 4 MB L2 to L3 (beta fully L3-resident, no HBM cost).
//  - dst index traffic halves again (read 4x not 8x); per-edge instruction
//    cost halves (32 lanes amortize one bpermute+load).
//  - R8 lesson: NO min-waves launch_bounds (VGPR 20 cap serialized loads).
// R7: bpermute broadcast + 32-bit voffset. R5: dst u16; packed epilogues.

#define M_ROWS 50000
#define DEG 32
#define NE (M_ROWS * DEG)
#define PAIR_DW (M_ROWS * 32)   // dwords per 128-B pair slice (6.4 MB)

typedef short s16x8 __attribute__((ext_vector_type(8)));
typedef float f32x4 __attribute__((ext_vector_type(4)));
typedef float f32x2 __attribute__((ext_vector_type(2)));
typedef unsigned int u32x2 __attribute__((ext_vector_type(2)));

__device__ __forceinline__ unsigned short f2bf(float f) {
  union { float f; unsigned int u; } c; c.f = f;
  unsigned int u = c.u;
  u += 0x7fffu + ((u >> 16) & 1u);   // round-to-nearest-even
  return (unsigned short)(u >> 16);
}

__device__ __forceinline__ float bfhi(unsigned int u) {
  return __uint_as_float(u & 0xffff0000u);
}
__device__ __forceinline__ float bflo(unsigned int u) {
  return __uint_as_float(u << 16);
}

__device__ __forceinline__ void gl_lds16(const void* g, void* l) {
  __builtin_amdgcn_global_load_lds(
      (const __attribute__((address_space(1))) unsigned int*)g,
      (__attribute__((address_space(3))) unsigned int*)l, 16, 0, 0);
}

// ---- K0a: x f32 -> bf16 (each thread: 8 elems) --------------------------
__global__ __launch_bounds__(256) void k_convert_x(
    const float* __restrict__ x, unsigned short* __restrict__ xb) {
  const size_t base = ((size_t)blockIdx.x * 256 + threadIdx.x) * 8;
  const float4 a = *(const float4*)(x + base);
  const float4 b = *(const float4*)(x + base + 4);
  union { unsigned short u[8]; uint4 v; } p;
  p.u[0] = f2bf(a.x); p.u[1] = f2bf(a.y); p.u[2] = f2bf(a.z); p.u[3] = f2bf(a.w);
  p.u[4] = f2bf(b.x); p.u[5] = f2bf(b.y); p.u[6] = f2bf(b.z); p.u[7] = f2bf(b.w);
  *(uint4*)(xb + base) = p.v;
}

// ---- K0b: W = [wc|wn] -> Wt[n][k] bf16 (transposed, k-contiguous) -------
__global__ __launch_bounds__(256) void k_convert_w(
    const float* __restrict__ wc, const float* __restrict__ wn,
    unsigned short* __restrict__ wt) {
  const int k = blockIdx.x;            // 0..511
  const int n4 = threadIdx.x * 4;      // 0..1020
  const float* src = (n4 < 512) ? (wc + (size_t)k * 512 + n4)
                                : (wn + (size_t)k * 512 + (n4 - 512));
  const float4 v = *(const float4*)src;
  wt[(size_t)(n4 + 0) * 512 + k] = f2bf(v.x);
  wt[(size_t)(n4 + 1) * 512 + k] = f2bf(v.y);
  wt[(size_t)(n4 + 2) * 512 + k] = f2bf(v.z);
  wt[(size_t)(n4 + 3) * 512 + k] = f2bf(v.w);
}

// ---- K0c: dst int32 -> u16 (N=50000 < 65536) ----------------------------
__global__ __launch_bounds__(256) void k_convert_dst(
    const int* __restrict__ dst, unsigned short* __restrict__ d16) {
  const size_t base = ((size_t)blockIdx.x * 256 + threadIdx.x) * 8;
  if (base >= NE) return;
  const int4 a = *(const int4*)(dst + base);
  const int4 b = *(const int4*)(dst + base + 4);
  union { unsigned short u[8]; uint4 v; } p;
  p.u[0] = (unsigned short)a.x; p.u[1] = (unsigned short)a.y;
  p.u[2] = (unsigned short)a.z; p.u[3] = (unsigned short)a.w;
  p.u[4] = (unsigned short)b.x; p.u[5] = (unsigned short)b.y;
  p.u[6] = (unsigned short)b.z; p.u[7] = (unsigned short)b.w;
  *(uint4*)(d16 + base) = p.v;
}

// ---- K1: bf16 MFMA GEMM, 128x128 tile, BK=64, swizzled LDS --------------
// 1D grid 3128 blocks, XCD-affine (mt,nt) mapping: XCD c = g%8 owns m-tiles
// {c, c+8, ...}, each with its 8 n-tiles consecutive -> A-tile L2 reuse.
// LDS layout: slot (row, seg) holds global k-segment seg^(row&7) -> all
// ds_read_b128 land 2 lanes/bank (free).
__global__ __launch_bounds__(256) void k_gemm(
    const unsigned short* __restrict__ xb,   // [M][512] bf16
    const unsigned short* __restrict__ wt,   // [1024][512] bf16
    const float* __restrict__ bias,          // [512]
    unsigned short* __restrict__ alphab,     // [M][8][32] u32 packed bf16
    unsigned char* __restrict__ betaf8) {    // [4][M][32] u32 packed fp8
  __shared__ __attribute__((aligned(16))) unsigned short As[128 * 64];
  __shared__ __attribute__((aligned(16))) unsigned short Bs[128 * 64];

  const int tid = threadIdx.x;
  const int g = blockIdx.x;
  int mt, nt;
  if (g < 3072) {
    const int c = g & 7, j = g >> 3;
    nt = j & 7; mt = (j >> 3) * 8 + c;
  } else {
    const int r = g - 3072;
    mt = 384 + (r >> 3); nt = r & 7;
  }
  const int n0 = nt * 128;
  const int m0 = mt * 128;

  const int wv = tid >> 6;
  const int l = tid & 63;
  const int lm = l & 15;
  const int quad = l >> 4;
  const int mb = (wv >> 1) * 64;
  const int nb = (wv & 1) * 64;

  // staging addresses (hoisted): 4 chunks each of A and B per thread
  size_t aofs[4], bofs[4];
  int ldst[4];
#pragma unroll
  for (int s = 0; s < 4; ++s) {
    const int c = s * 256 + tid;
    const int row = c >> 3;              // 0..127
    const int seg = c & 7;               // LDS slot segment
    const int sg = seg ^ (row & 7);      // global segment fetched into it
    int am = m0 + row; if (am >= M_ROWS) am = M_ROWS - 1;
    aofs[s] = (size_t)am * 512 + sg * 8;
    bofs[s] = (size_t)(n0 + row) * 512 + sg * 8;
    ldst[s] = (s * 256 + (tid & ~63)) * 16;
  }

  f32x4 acc[4][4];
#pragma unroll
  for (int i = 0; i < 4; ++i)
#pragma unroll
    for (int j = 0; j < 4; ++j) acc[i][j] = (f32x4)(0.0f);

  for (int kt = 0; kt < 8; ++kt) {
    const int k0 = kt * 64;
    __syncthreads();
#pragma unroll
    for (int s = 0; s < 4; ++s) {
      gl_lds16(xb + aofs[s] + k0, (char*)As + ldst[s]);
      gl_lds16(wt + bofs[s] + k0, (char*)Bs + ldst[s]);
    }
    __syncthreads();   // drains vmcnt for global_load_lds

#pragma unroll
    for (int h = 0; h < 2; ++h) {
      s16x8 af[4], bfr[4];
#pragma unroll
      for (int i = 0; i < 4; ++i) {
        const int R = mb + 16 * i + lm;
        af[i] = *(const s16x8*)&As[R * 64 + (((h * 4 + quad) ^ (R & 7)) << 3)];
      }
#pragma unroll
      for (int j = 0; j < 4; ++j) {
        const int R = nb + 16 * j + lm;
        bfr[j] = *(const s16x8*)&Bs[R * 64 + (((h * 4 + quad) ^ (R & 7)) << 3)];
      }
#pragma unroll
      for (int i = 0; i < 4; ++i)
#pragma unroll
        for (int j = 0; j < 4; ++j)
          acc[i][j] = __builtin_amdgcn_mfma_f32_16x16x32_bf16(
              af[i], bfr[j], acc[i][j], 0, 0, 0);
    }
  }

  // Packed epilogue. grp64 = global 64-channel group (0..15).
  // Within a group, dword d holds channels {d, 16+d, 32+d, 48+d} = lane
  // lm's j=0..3 accumulator columns -> no cross-lane traffic needed.
  // Beta rows are 128 B: pair slice [pair][m][32 dw], dword = g*16 + lm
  // where g = 64-group within the pair.
  const bool isAlpha = (n0 < 512);
  const int grp64 = (n0 + nb) >> 6;
  float b4[4];
#pragma unroll
  for (int j = 0; j < 4; ++j)
    b4[j] = isAlpha ? bias[n0 + nb + 16 * j + lm] : 0.0f;

  if (isAlpha) {
    unsigned int* ap = (unsigned int*)alphab;   // [M][8][32] dwords
#pragma unroll
    for (int i = 0; i < 4; ++i) {
#pragma unroll
      for (int r = 0; r < 4; ++r) {
        const int m = m0 + mb + 16 * i + quad * 4 + r;
        if (m < M_ROWS) {
          u32x2 v;
          v.x = (unsigned int)f2bf(acc[i][0][r] + b4[0]) |
                ((unsigned int)f2bf(acc[i][1][r] + b4[1]) << 16);
          v.y = (unsigned int)f2bf(acc[i][2][r] + b4[2]) |
                ((unsigned int)f2bf(acc[i][3][r] + b4[3]) << 16);
          *(u32x2*)(ap + (size_t)m * 256 + grp64 * 32 + 2 * lm) = v;
        }
      }
    }
  } else {
    const int pr = grp64 - 8;                       // 0..7
    unsigned int* bp = (unsigned int*)betaf8 + (size_t)(pr >> 1) * PAIR_DW;
    const int g16 = (pr & 1) * 16;
#pragma unroll
    for (int i = 0; i < 4; ++i) {
#pragma unroll
      for (int r = 0; r < 4; ++r) {
        const int m = m0 + mb + 16 * i + quad * 4 + r;
        if (m < M_ROWS) {
          int p = __builtin_amdgcn_cvt_pk_fp8_f32(acc[i][0][r], acc[i][1][r], 0, false);
          p = __builtin_amdgcn_cvt_pk_fp8_f32(acc[i][2][r], acc[i][3][r], p, true);
          bp[(size_t)m * 32 + g16 + lm] = (unsigned int)p;
        }
      }
    }
  }
}

// ---- K2: out = alpha + mean(beta_fp8 rows), 128-B rows, 4 pairs ---------
// Grid 50000 blocks; pair = b&3 -> XCDs {pair, pair+4} serve each 6.4 MB
// pair slice (L2 ~62% hit, misses -> L3, beta fully L3-resident).
// Wave = 1 node x 1 pair: two 32-lane groups walk 16 edges each, one
// line-aligned 128-B load per edge; shfl_xor(32) merge; lanes 0-31 write.
template <typename IT>
__global__ __launch_bounds__(256) void k_gather(
    const IT* __restrict__ dst, const unsigned int* __restrict__ beta32,
    const unsigned int* __restrict__ alpha32, float* __restrict__ out) {
  const int b = blockIdx.x;              // 0..49999
  const int pair = b & 3;                // phase-pair; XCD = b&7 = pair(+4)
  const int q = b >> 2;                  // 0..12499
  const int tid = threadIdx.x;
  const int w = tid >> 6;
  const int l = tid & 63;
  const int lm2 = l & 31;                // dword in 128-B row
  const int node = q * 4 + w;

  // lane stages one of the node's 32 edge indices (duplicated in both halves)
  const int vstage = (int)(unsigned)__builtin_nontemporal_load(
      dst + (size_t)node * 32 + lm2);

  const char* base = (const char*)(beta32 + (size_t)pair * PAIR_DW);
  const int abase = (l & 32) * 6;        // grp A: src lanes 0-15; B: 48-63
  const unsigned lmoff = (unsigned)lm2 * 4u;

  f32x2 s01 = (f32x2)(0.0f), s23 = (f32x2)(0.0f);
#pragma unroll
  for (int h = 0; h < 2; ++h) {
    unsigned int bb[8];
#pragma unroll
    for (int e = 0; e < 8; ++e) {
      const int row = __builtin_amdgcn_ds_bpermute(
          abase + ((h * 8 + e) << 2), vstage);
      bb[e] = *(const unsigned int*)(base + (((unsigned)row << 7) + lmoff));
    }
#pragma unroll
    for (int e = 0; e < 8; ++e) {
      s01 += __builtin_amdgcn_cvt_pk_f32_fp8(bb[e], false);
      s23 += __builtin_amdgcn_cvt_pk_f32_fp8(bb[e], true);
    }
  }

  // merge the two 16-edge halves (lanes l <-> l^32)
  s01.x += __shfl_xor(s01.x, 32, 64);
  s01.y += __shfl_xor(s01.y, 32, 64);
  s23.x += __shfl_xor(s23.x, 32, 64);
  s23.y += __shfl_xor(s23.y, 32, 64);

  if (l < 32) {
    const int g = l >> 4;                // 64-group within the pair
    const int lm = l & 15;
    const u32x2 av = __builtin_nontemporal_load(
        (const u32x2*)(alpha32 + (size_t)node * 256 + (pair * 2 + g) * 32) + lm);
    const float s = 1.0f / 32.0f;
    float* ob = out + (size_t)node * 512 + pair * 128 + g * 64;
    __builtin_nontemporal_store(bflo(av.x) + s01.x * s, ob + lm);
    __builtin_nontemporal_store(bfhi(av.x) + s01.y * s, ob + 16 + lm);
    __builtin_nontemporal_store(bflo(av.y) + s23.x * s, ob + 32 + lm);
    __builtin_nontemporal_store(bfhi(av.y) + s23.y * s, ob + 48 + lm);
  }
}

extern "C" void kernel_launch(void* const* d_in, const int* in_sizes, int n_in,
                              void* d_out, int out_size, void* d_ws, size_t ws_size,
                              hipStream_t stream) {
  const float* x    = (const float*)d_in[0];
  const float* wc   = (const float*)d_in[1];
  const float* wn   = (const float*)d_in[2];
  const float* bias = (const float*)d_in[3];
  const int*   ei   = (const int*)d_in[4];   // [2][E] int32; dst = ei + E
  float* out = (float*)d_out;

  char* ws = (char*)d_ws;
  unsigned short* xb     = (unsigned short*)ws;                  // 51,200,000 B
  unsigned short* wt     = (unsigned short*)(ws + 51200000);     //  1,048,576 B
  unsigned short* alphab = (unsigned short*)(ws + 52248576);     // 51,200,000 B
  unsigned char*  betaf8 = (unsigned char*)(ws + 103448576);     // 25,600,000 B
  unsigned short* d16    = (unsigned short*)(ws + 129048576);    //  3,200,000 B
  const bool u16ok = (ws_size >= (size_t)129048576 + 3200000);

  k_convert_x<<<12500, 256, 0, stream>>>(x, xb);
  k_convert_w<<<512, 256, 0, stream>>>(wc, wn, wt);
  if (u16ok) k_convert_dst<<<782, 256, 0, stream>>>(ei + NE, d16);
  k_gemm<<<3128, 256, 0, stream>>>(xb, wt, bias, alphab, betaf8);
  if (u16ok) {
    k_gather<unsigned short><<<50000, 256, 0, stream>>>(
        d16, (const unsigned int*)betaf8, (const unsigned int*)alphab, out);
  } else {
    k_gather<int><<<50000, 256, 0, stream>>>(
        ei + NE, (const unsigned int*)betaf8, (const unsigned int*)alphab, out);
  }
}